// Round 3
// baseline (2052.957 us; speedup 1.0000x reference)
//
#include <hip/hip_runtime.h>
#include <math.h>

#define N_TOK 4096
#define EMB   768
#define NH    12
#define HD    64
#define FFN   3072
#define LN_EPS 1e-5f

// ---------------------------------------------------------------------------
// Generic fp32 GEMM: C = A(MxK) @ B(KxN) (+bias) (+relu). 64x64 tile, BK=16,
// 256 threads, 4x4 micro-tile per thread, float4 global + LDS reads.
// ---------------------------------------------------------------------------
template<bool RELU, bool BIAS>
__global__ __launch_bounds__(256) void gemm_kernel(
    const float* __restrict__ A, const float* __restrict__ B,
    const float* __restrict__ bias, float* __restrict__ C,
    int M, int K, int N)
{
    constexpr int BM = 64, BN = 64, BK = 16;
    __shared__ float As[BK][BM + 4];   // stored transposed: As[k][m]
    __shared__ float Bs[BK][BN + 4];   // Bs[k][n]; row stride 68 floats = 16B aligned

    const int tx = threadIdx.x & 15;   // col group
    const int ty = threadIdx.x >> 4;   // row group
    const int row0 = blockIdx.y * BM;
    const int col0 = blockIdx.x * BN;

    float acc[4][4] = {};

    for (int k0 = 0; k0 < K; k0 += BK) {
        // load A tile 64x16 (float4 along K), store transposed
        {
            const int r  = threadIdx.x >> 2;        // 0..63
            const int kc = (threadIdx.x & 3) * 4;   // 0,4,8,12
            float4 a = *(const float4*)&A[(size_t)(row0 + r) * K + k0 + kc];
            As[kc + 0][r] = a.x; As[kc + 1][r] = a.y;
            As[kc + 2][r] = a.z; As[kc + 3][r] = a.w;
        }
        // load B tile 16x64 (float4 along N)
        {
            const int r = threadIdx.x >> 4;         // 0..15
            const int c = (threadIdx.x & 15) * 4;   // 0..60
            float4 b = *(const float4*)&B[(size_t)(k0 + r) * N + col0 + c];
            *(float4*)&Bs[r][c] = b;
        }
        __syncthreads();
        #pragma unroll
        for (int kk = 0; kk < BK; ++kk) {
            float4 a4 = *(const float4*)&As[kk][ty * 4];
            float4 b4 = *(const float4*)&Bs[kk][tx * 4];
            float a[4] = {a4.x, a4.y, a4.z, a4.w};
            float b[4] = {b4.x, b4.y, b4.z, b4.w};
            #pragma unroll
            for (int i = 0; i < 4; ++i)
                #pragma unroll
                for (int j = 0; j < 4; ++j)
                    acc[i][j] += a[i] * b[j];
        }
        __syncthreads();
    }

    #pragma unroll
    for (int i = 0; i < 4; ++i) {
        const int r = row0 + ty * 4 + i;
        const int c = col0 + tx * 4;
        float4 v;
        float* vv = &v.x;
        #pragma unroll
        for (int j = 0; j < 4; ++j) {
            float t = acc[i][j];
            if (BIAS) t += bias[c + j];
            if (RELU) t = fmaxf(t, 0.0f);
            vv[j] = t;
        }
        *(float4*)&C[(size_t)r * N + c] = v;
    }
}

// ---------------------------------------------------------------------------
// Causal flash attention, fp32. One block = one head x 16 queries.
// 4 waves, 4 queries/wave. Key tiles of 64. Online softmax.
// Q/K/V per head are contiguous 4096x64 row-major slabs (faithful reshape).
// ---------------------------------------------------------------------------
#define QB 16
#define QW 4
#define KT 64

__global__ __launch_bounds__(256) void attn_kernel(
    const float* __restrict__ Qm, const float* __restrict__ Km,
    const float* __restrict__ Vm, float* __restrict__ ctx2)
{
    __shared__ float Ks[KT][HD + 1];     // (key, d), pad 1 -> conflict-free scalar reads
    __shared__ float Vs[KT][HD];         // (key, d)
    __shared__ float qs[QB][HD];         // pre-scaled by 1/8
    __shared__ float ps[4][QW][KT];      // per-wave P values

    const int h  = blockIdx.y;
    const int q0 = blockIdx.x * QB;
    const float* Qh = Qm + (size_t)h * N_TOK * HD;
    const float* Kh = Km + (size_t)h * N_TOK * HD;
    const float* Vh = Vm + (size_t)h * N_TOK * HD;

    const int t    = threadIdx.x;
    const int wave = t >> 6;
    const int lane = t & 63;

    // load 16 query rows, scaled by 1/sqrt(HD)=0.125
    {
        float4 q = *(const float4*)&Qh[(size_t)q0 * HD + t * 4];
        float* dst = &qs[0][0];
        dst[t * 4 + 0] = q.x * 0.125f; dst[t * 4 + 1] = q.y * 0.125f;
        dst[t * 4 + 2] = q.z * 0.125f; dst[t * 4 + 3] = q.w * 0.125f;
    }

    float m[QW], lsum[QW], ctx[QW];
    #pragma unroll
    for (int i = 0; i < QW; ++i) { m[i] = -INFINITY; lsum[i] = 0.f; ctx[i] = 0.f; }

    const int qmax   = q0 + QB - 1;
    const int ntiles = (qmax >> 6) + 1;

    for (int kt = 0; kt < ntiles; ++kt) {
        const int kbase = kt * KT;
        __syncthreads();   // protect Ks/Vs reuse
        // cooperative load of K,V tiles (64x64 each)
        {
            const int r = t >> 2;            // key row 0..63
            const int c = (t & 3) * 16;      // 16 floats per thread per matrix
            #pragma unroll
            for (int u = 0; u < 16; u += 4) {
                float4 k4 = *(const float4*)&Kh[(size_t)(kbase + r) * HD + c + u];
                Ks[r][c + u + 0] = k4.x; Ks[r][c + u + 1] = k4.y;
                Ks[r][c + u + 2] = k4.z; Ks[r][c + u + 3] = k4.w;
                float4 v4 = *(const float4*)&Vh[(size_t)(kbase + r) * HD + c + u];
                *(float4*)&Vs[r][c + u] = v4;
            }
        }
        __syncthreads();

        // ---- score phase: lane = key index ----
        float s[QW] = {0.f, 0.f, 0.f, 0.f};
        #pragma unroll 16
        for (int d = 0; d < HD; ++d) {
            float kv = Ks[lane][d];
            #pragma unroll
            for (int qq = 0; qq < QW; ++qq)
                s[qq] += qs[wave * QW + qq][d] * kv;   // qs read is broadcast
        }

        const int kg = kbase + lane;
        #pragma unroll
        for (int qq = 0; qq < QW; ++qq) {
            const int qg = q0 + wave * QW + qq;
            float sv = (kg <= qg) ? s[qq] : -INFINITY;
            // wave-wide max
            float tm = sv;
            #pragma unroll
            for (int off = 32; off >= 1; off >>= 1)
                tm = fmaxf(tm, __shfl_xor(tm, off));
            const float mn    = fmaxf(m[qq], tm);
            const float alpha = __expf(m[qq] - mn);    // exp(-inf)=0 on first tile
            const float p     = __expf(sv - mn);       // masked lanes -> 0
            float psum = p;
            #pragma unroll
            for (int off = 32; off >= 1; off >>= 1)
                psum += __shfl_xor(psum, off);
            lsum[qq] = lsum[qq] * alpha + psum;
            m[qq]    = mn;
            ctx[qq] *= alpha;                          // alpha is wave-uniform
            ps[wave][qq][lane] = p;                    // same-wave LDS, no barrier needed
        }

        // ---- PV phase: lane = d ----
        #pragma unroll 16
        for (int j = 0; j < KT; ++j) {
            float vv = Vs[j][lane];
            #pragma unroll
            for (int qq = 0; qq < QW; ++qq)
                ctx[qq] += ps[wave][qq][j] * vv;       // ps read is broadcast
        }
    }

    // epilogue: ctx2[q, h*64 + d] = ctx / lsum
    #pragma unroll
    for (int qq = 0; qq < QW; ++qq) {
        const int qg = q0 + wave * QW + qq;
        ctx2[(size_t)qg * EMB + h * HD + lane] = ctx[qq] / lsum[qq];
    }
}

// ---------------------------------------------------------------------------
// Fused residual + LayerNorm: out = LN(a + b) * g + beta. One block per row.
// ---------------------------------------------------------------------------
__global__ __launch_bounds__(256) void ln_kernel(
    const float* __restrict__ a, const float* __restrict__ b,
    const float* __restrict__ g, const float* __restrict__ beta,
    float* __restrict__ out)
{
    const int row = blockIdx.x;
    const int t = threadIdx.x;
    float v[3];
    float sum = 0.f, sumsq = 0.f;
    #pragma unroll
    for (int i = 0; i < 3; ++i) {
        const int c = t + i * 256;
        const float x = a[(size_t)row * EMB + c] + b[(size_t)row * EMB + c];
        v[i] = x; sum += x; sumsq += x * x;
    }
    #pragma unroll
    for (int off = 32; off >= 1; off >>= 1) {
        sum   += __shfl_xor(sum, off);
        sumsq += __shfl_xor(sumsq, off);
    }
    __shared__ float ws[8];
    const int wave = t >> 6, lane = t & 63;
    if (lane == 0) { ws[wave] = sum; ws[4 + wave] = sumsq; }
    __syncthreads();
    sum   = ws[0] + ws[1] + ws[2] + ws[3];
    sumsq = ws[4] + ws[5] + ws[6] + ws[7];
    const float mu  = sum * (1.0f / EMB);
    const float var = sumsq * (1.0f / EMB) - mu * mu;
    const float rs  = rsqrtf(var + LN_EPS);
    #pragma unroll
    for (int i = 0; i < 3; ++i) {
        const int c = t + i * 256;
        out[(size_t)row * EMB + c] = (v[i] - mu) * rs * g[c] + beta[c];
    }
}

// ---------------------------------------------------------------------------
extern "C" void kernel_launch(void* const* d_in, const int* in_sizes, int n_in,
                              void* d_out, int out_size, void* d_ws, size_t ws_size,
                              hipStream_t stream)
{
    (void)in_sizes; (void)n_in; (void)out_size; (void)ws_size;
    const float* x     = (const float*)d_in[0];
    const float* Wq    = (const float*)d_in[1];
    const float* Wk    = (const float*)d_in[2];
    const float* Wv    = (const float*)d_in[3];
    const float* Wo    = (const float*)d_in[4];
    const float* W1    = (const float*)d_in[5];
    const float* b1    = (const float*)d_in[6];
    const float* W2    = (const float*)d_in[7];
    const float* b2    = (const float*)d_in[8];
    const float* g1    = (const float*)d_in[9];
    const float* beta1 = (const float*)d_in[10];
    const float* g2    = (const float*)d_in[11];
    const float* beta2 = (const float*)d_in[12];
    float* out = (float*)d_out;

    const size_t NE = (size_t)N_TOK * EMB;   // 3,145,728
    float* ws  = (float*)d_ws;
    float* Q   = ws;            // NE
    float* K   = Q  + NE;       // NE
    float* V   = K  + NE;       // NE
    float* ctx = V  + NE;       // NE
    float* tmp = ctx + NE;      // NE (attn_out, later ff2)
    float* h1  = tmp + NE;      // NE
    float* ff1 = Q;             // N*FFN = 4*NE, aliases Q..ctx (free after attention)

    const dim3 blk(256);
    const dim3 gE(EMB / 64, N_TOK / 64);    // (12, 64)
    const dim3 gF(FFN / 64, N_TOK / 64);    // (48, 64)

    // QKV projections
    gemm_kernel<false, false><<<gE, blk, 0, stream>>>(x, Wq, nullptr, Q, N_TOK, EMB, EMB);
    gemm_kernel<false, false><<<gE, blk, 0, stream>>>(x, Wk, nullptr, K, N_TOK, EMB, EMB);
    gemm_kernel<false, false><<<gE, blk, 0, stream>>>(x, Wv, nullptr, V, N_TOK, EMB, EMB);

    // causal attention -> ctx (already head-recombined)
    attn_kernel<<<dim3(N_TOK / QB, NH), blk, 0, stream>>>(Q, K, V, ctx);

    // output projection
    gemm_kernel<false, false><<<gE, blk, 0, stream>>>(ctx, Wo, nullptr, tmp, N_TOK, EMB, EMB);

    // h1 = LN(x + attn_out)
    ln_kernel<<<dim3(N_TOK), blk, 0, stream>>>(x, tmp, g1, beta1, h1);

    // ff1 = relu(h1 @ W1 + b1)
    gemm_kernel<true, true><<<gF, blk, 0, stream>>>(h1, W1, b1, ff1, N_TOK, EMB, FFN);

    // ff2 = ff1 @ W2 + b2 -> tmp
    gemm_kernel<false, true><<<gE, blk, 0, stream>>>(ff1, W2, b2, tmp, N_TOK, FFN, EMB);

    // out = LN(h1 + ff2)
    ln_kernel<<<dim3(N_TOK), blk, 0, stream>>>(h1, tmp, g2, beta2, out);
}